// Round 9
// baseline (171.068 us; speedup 1.0000x reference)
//
#include <hip/hip_runtime.h>
#include <math.h>

#define DIMH 256        // D
#define NB   32         // batch
#define E_TOT 43234
#define TE   16         // entities per block (2703 blocks = 10.6/CU)
#define DK   16         // dims per chunk
#define NCW  4          // chunks per wave (4 waves x 4 chunks x 16 dims = 256 = D)

typedef float v2f __attribute__((ext_vector_type(2)));
typedef float v4f __attribute__((ext_vector_type(4)));
typedef __fp16 v2h __attribute__((ext_vector_type(2)));
typedef __fp16 v4h __attribute__((ext_vector_type(4)));

// Kernel 1: rotate head by relation phase. LAYOUT CHANGE (r9): emit
// DIM-INTERLEAVED (re_d0, im_d0, re_d1, im_d1) per float4 so each v2h in
// LDS is one dim's (re,im) pair -> inner loop uses v_dot2_f32_f16.
// sincos via HW trans unit in REVOLUTIONS: rev = rel * 16 exactly.
__global__ __launch_bounds__(64) void rot_kernel(const float* __restrict__ head,
                                                 const float* __restrict__ rel,
                                                 float4* __restrict__ rot_v4) {
    int i  = blockIdx.x * 64 + threadIdx.x;   // 0..4095
    int b  = i >> 7;
    int dp = i & 127;
    int d0 = dp * 2;
    float4 w;
    {
        float re_h = head[b * 2 * DIMH + d0];
        float im_h = head[b * 2 * DIMH + DIMH + d0];
        float x = rel[b * DIMH + d0] * 16.0f;       // revolutions
        float f = x - floorf(x);
        float s = __builtin_amdgcn_sinf(f);
        float c = __builtin_amdgcn_cosf(f);
        w.x = re_h * c - im_h * s;                  // re(d0)
        w.y = re_h * s + im_h * c;                  // im(d0)
    }
    {
        float re_h = head[b * 2 * DIMH + d0 + 1];
        float im_h = head[b * 2 * DIMH + DIMH + d0 + 1];
        float x = rel[b * DIMH + d0 + 1] * 16.0f;
        float f = x - floorf(x);
        float s = __builtin_amdgcn_sinf(f);
        float c = __builtin_amdgcn_cosf(f);
        w.z = re_h * c - im_h * s;                  // re(d1)
        w.w = re_h * s + im_h * c;                  // im(d1)
    }
    rot_v4[b * (DIMH / 2) + dp] = w;
}

__device__ __forceinline__ v2h pkrtz(float a, float b) {
    return __builtin_amdgcn_cvt_pkrtz(a, b);
}

#if __has_builtin(__builtin_amdgcn_fdot2)
__device__ __forceinline__ float dot2(v2h a, v2h b, float c) {
    return __builtin_amdgcn_fdot2(a, b, c, false);
}
#else
__device__ __forceinline__ float dot2(v2h a, v2h b, float c) {
    return (float)a.x * (float)b.x + (float)a.y * (float)b.y + c;
}
#endif

// ROUND-8 POST-MORTEM: issue-bound confirmed (busy 53us of 73.5 wall), but
// per-contrib-pair cost measured ~47 cyc vs ideal ~26: the v2h sqrt path
// scalarizes (extract-hi, 2x v_sqrt_f16, repack) + f16 sub-acc init/flush.
// ROUND 9: dim-interleaved (re,im) v2h pairs + v_dot2_f32_f16:
// per dim = pk_sub + dot2 + v_sqrt_f32 + v_add_f32 (f32 acc, no flush,
// no repack) = 28 cyc per 2 dims. Predicted issue ~35us, wall ~50-57us.
// Structure held from r8: TE=16, 4 waves, wave-private 3KB zones, zero
// main-loop barriers, XOR swizzle, 2-barrier reduction epilogue.
__global__ __launch_bounds__(256) void dist_kernel(const float* __restrict__ ent,
                                                   const float4* __restrict__ rot_v4,
                                                   float* __restrict__ out) {
    __shared__ v4h smem[1536];   // 12288 B: 4 zones x 3 KB; reduction overlay 9.2 KB

    const int tid  = threadIdx.x;
    const int lane = tid & 63;
    const int w    = tid >> 6;
    const int eb   = blockIdx.x * TE;
    const int eg   = lane & 7;         // entity group: entities 2eg, 2eg+1
    const int bg   = lane >> 3;        // batch group: batches 4bg..4bg+3

    v4h* se = smem + w * 384;          // [16 rows][8 cols] v4h, row = entity
    v4h* sr = se + 128;                // [32 rows][8 cols] v4h, row = batch

    // staging task maps (per wave, per chunk)
    const int erow = lane >> 2;        // ent row 0..15
    const int eq   = lane & 3;         // float4-quad within the 16-dim chunk
    const int rb   = lane >> 3;        // rot batches rb, rb+8, rb+16, rb+24
    const int rdpi = lane & 7;         // dim-pair within chunk

    const int c0 = w * NCW;            // first global chunk for this wave

    float4 pe_re, pe_im, pr[4];

    auto load_chunk = [&](int c) {     // c = global chunk id (dims 16c..16c+15)
        const int dk = c * DK;
        int er = min(eb + erow, E_TOT - 1);
        const float* b0 = ent + (size_t)er * (2 * DIMH);
        pe_re = *reinterpret_cast<const float4*>(b0 + dk + 4 * eq);
        pe_im = *reinterpret_cast<const float4*>(b0 + DIMH + dk + 4 * eq);
        #pragma unroll
        for (int s = 0; s < 4; ++s)
            pr[s] = rot_v4[(rb + 8 * s) * (DIMH / 2) + c * (DK / 2) + rdpi];
    };

    auto store_chunk = [&]() {
        {
            int row = erow;
            int sw  = (row >> 1) & 7;                // 0..7
            v4h lo, hi;                              // (re_d, im_d) interleave
            lo.xy = pkrtz(pe_re.x, pe_im.x);         // dim d0
            lo.zw = pkrtz(pe_re.y, pe_im.y);         // dim d1
            hi.xy = pkrtz(pe_re.z, pe_im.z);         // dim d2
            hi.zw = pkrtz(pe_re.w, pe_im.w);         // dim d3
            se[row * 8 + ((2 * eq)     ^ sw)] = lo;
            se[row * 8 + ((2 * eq + 1) ^ sw)] = hi;
        }
        #pragma unroll
        for (int s = 0; s < 4; ++s) {
            int b  = rb + 8 * s;
            int sw = (b >> 2) & 7;                   // 0..7
            v4h r;                                   // rot already interleaved
            r.xy = pkrtz(pr[s].x, pr[s].y);          // (re_d0, im_d0)
            r.zw = pkrtz(pr[s].z, pr[s].w);          // (re_d1, im_d1)
            sr[b * 8 + (rdpi ^ sw)] = r;
        }
    };

    float acc[4][2];   // scalar f32 accumulators — static indices only
    #pragma unroll
    for (int j = 0; j < 4; ++j)
        #pragma unroll
        for (int k = 0; k < 2; ++k) acc[j][k] = 0.f;

    load_chunk(c0);

    #pragma unroll 1
    for (int cc = 0; cc < NCW; ++cc) {
        store_chunk();                            // regs (chunk c0+cc) -> LDS
        if (cc + 1 < NCW) load_chunk(c0 + cc + 1);

        #pragma unroll 4
        for (int p = 0; p < DK / 2; ++p) {
            int pe = p ^ eg, pb = p ^ bg;
            v4h r0 = sr[(4 * bg + 0) * 8 + pb];
            v4h r1 = sr[(4 * bg + 1) * 8 + pb];
            v4h r2 = sr[(4 * bg + 2) * 8 + pb];
            v4h r3 = sr[(4 * bg + 3) * 8 + pb];
            v4h e0 = se[(2 * eg + 0) * 8 + pe];
            v4h e1 = se[(2 * eg + 1) * 8 + pe];
            // per 2 dims: 2 pk_sub + 2 dot2 + 2 v_sqrt_f32 + adds
            #define CONTRIB(J, K, R, E)                                   \
                { v2h a = R.xy - E.xy;                                    \
                  v2h b = R.zw - E.zw;                                    \
                  float s0 = dot2(a, a, 0.f);                             \
                  float s1 = dot2(b, b, 0.f);                             \
                  acc[J][K] += __builtin_amdgcn_sqrtf(s0)                 \
                             + __builtin_amdgcn_sqrtf(s1); }
            CONTRIB(0,0,r0,e0) CONTRIB(0,1,r0,e1)
            CONTRIB(1,0,r1,e0) CONTRIB(1,1,r1,e1)
            CONTRIB(2,0,r2,e0) CONTRIB(2,1,r2,e1)
            CONTRIB(3,0,r3,e0) CONTRIB(3,1,r3,e1)
            #undef CONTRIB
        }
    }

    // ---- cross-wave reduction: 4 d-partials per (b,e) ----
    float part[8];
    #pragma unroll
    for (int j = 0; j < 4; ++j)
        #pragma unroll
        for (int k = 0; k < 2; ++k)
            part[j * 2 + k] = acc[j][k];

    __syncthreads();                       // all waves done reading staging LDS
    float* red = (float*)smem;             // 256 x 9 floats = 9216 B, fits
    #pragma unroll
    for (int i = 0; i < 8; ++i)
        red[tid * 9 + i] = part[i];        // stride 9: gcd(9,32)=1 -> spread
    __syncthreads();

    // 512 outputs, 2/thread; consecutive threads -> consecutive entities
    #pragma unroll
    for (int t = 0; t < 2; ++t) {
        int O  = tid + 256 * t;
        int b  = O >> 4;                   // 0..31
        int ei = O & 15;
        int e  = eb + ei;
        if (e < E_TOT) {
            int lane_src = ((b >> 2) << 3) + (ei >> 1);   // bg*8 + eg
            int idx      = ((b & 3) << 1) + (ei & 1);     // j*2 + k
            float sum = red[(0 * 64 + lane_src) * 9 + idx]
                      + red[(1 * 64 + lane_src) * 9 + idx]
                      + red[(2 * 64 + lane_src) * 9 + idx]
                      + red[(3 * 64 + lane_src) * 9 + idx];
            out[(size_t)b * E_TOT + e] = 6.0f - sum;
        }
    }
}

extern "C" void kernel_launch(void* const* d_in, const int* in_sizes, int n_in,
                              void* d_out, int out_size, void* d_ws, size_t ws_size,
                              hipStream_t stream) {
    const float* head = (const float*)d_in[0];   // (32, 512)
    const float* rel  = (const float*)d_in[1];   // (32, 256)
    const float* ent  = (const float*)d_in[2];   // (43234, 512)
    float4* rot_v4 = (float4*)d_ws;              // 32 * 128 * 16 B = 64 KB

    rot_kernel<<<(NB * DIMH / 2) / 64, 64, 0, stream>>>(head, rel, rot_v4);

    int etiles = (E_TOT + TE - 1) / TE;          // 2703
    dist_kernel<<<etiles, 256, 0, stream>>>(ent, rot_v4, (float*)d_out);
}